// Round 2
// baseline (180.559 us; speedup 1.0000x reference)
//
#include <hip/hip_runtime.h>

// EnhancedMemoryStack: B=32768, S=16, D=64. fp32 I/O; bf16 MFMA internally.
//
// Key algebra:
//   scores = qhat . khat^T = xhat (Q K^T) xhat^T = xhat M xhat^T, M precomputed (128x128)
//   z_read = sum_s np[s] (attn . vhat)[s] = sum_t w[t] vhat[t], w[t] = sum_s np[s] attn[s][t]
// -> per batch: y = xhat M (32 MFMAs), scores = y xhat^T (4, B-operand in regs),
//    vhat (32), readout from C-layout regs. No PV matmul, no attn/v^T staging.
//
// 512-thr WG (8 waves, one batch each): LDS = M(32K) + Wv(16K) + 8x4K y-stage = 80KB
// -> 2 WG/CU = 16 waves/CU.
//
// d_ws layout: [0..4) active-slot counter, [1024..33792) M^T bf16 (needs ws_size >= 33792).

typedef __bf16 bf16x8 __attribute__((ext_vector_type(8)));
typedef float  f32x4  __attribute__((ext_vector_type(4)));

#define B_TOT   32768
#define GRID_WG 512
#define NWAVES  4096            // 512 WG * 8 waves
#define BPW     8               // batches per wave

__device__ __forceinline__ unsigned short f2bf(float x) {
  __bf16 h = (__bf16)x;
  return __builtin_bit_cast(unsigned short, h);
}
__device__ __forceinline__ float sigm(float x) { return 1.0f / (1.0f + expf(-x)); }

__global__ void ems_zero(unsigned int* c) { if (threadIdx.x == 0) *c = 0u; }

__global__ void ems_fin(const unsigned int* __restrict__ c, float* __restrict__ out) {
  if (threadIdx.x == 0) out[0] = (float)(*c) * (1.0f / 32768.0f);
}

// Mt[e2][e] = M[e][e2] = sum_{E'} Q[e][E'] K[e2][E']
// Q[e][E'] (qhat = xhat Q):  E'<64: (e<64 ?  Wqr[E'][e] : -Wqi[E'][e-64])
//                            E'>=64:(e<64 ?  Wqi[E'-64][e] : Wqr[E'-64][e-64])
// K[e2][E'] analogous with Wk.
__global__ void __launch_bounds__(128)
ems_mt(const float* __restrict__ wqr, const float* __restrict__ wqi,
       const float* __restrict__ wkr, const float* __restrict__ wki,
       unsigned short* __restrict__ mt)
{
  __shared__ float sK[128];
  const int e2 = (int)blockIdx.x;
  const int e  = (int)threadIdx.x;
  float kv;
  if (e < 64) kv = (e2 < 64) ? wkr[e*64 + e2]      : -wki[e*64 + (e2-64)];
  else        kv = (e2 < 64) ? wki[(e-64)*64 + e2] :  wkr[(e-64)*64 + (e2-64)];
  sK[e] = kv;
  __syncthreads();
  float acc = 0.0f;
  #pragma unroll 8
  for (int Ep = 0; Ep < 64; ++Ep) {
    float q = (e < 64) ? wqr[Ep*64 + e] : -wqi[Ep*64 + (e-64)];
    acc += q * sK[Ep];
  }
  #pragma unroll 8
  for (int Ep = 0; Ep < 64; ++Ep) {
    float q = (e < 64) ? wqi[Ep*64 + e] : wqr[Ep*64 + (e-64)];
    acc += q * sK[64 + Ep];
  }
  mt[e2*128 + e] = f2bf(acc);
}

__global__ void __launch_bounds__(512, 4)
ems_main(const float* __restrict__ z_real, const float* __restrict__ z_imag,
         const float* __restrict__ mem,    const float* __restrict__ ptrv,
         const float* __restrict__ ctrl,
         const float* __restrict__ wvr,    const float* __restrict__ wvi,
         const unsigned short* __restrict__ mt,
         float* __restrict__ out_zr, float* __restrict__ out_zi,
         float* __restrict__ out_mem, float* __restrict__ out_ptr,
         unsigned int* __restrict__ ws_cnt)
{
  // [0..16384)       Mt bf16 [e2][e], 16B-chunk XOR swizzle: chunk ^ (e2&15)
  // [16384..24576)   Wv_r, Wv_i bf16 [e][d], chunk ^ (e&7)
  // [24576..40960)   per-wave y-stage: [16 rows][128 cols] bf16, chunk ^ (row&15)
  __shared__ __align__(16) unsigned short lds[40960];

  const int tid = (int)threadIdx.x;

  for (int idx = tid; idx < 16384; idx += 512) {
    int e2 = idx >> 7, e = idx & 127;
    lds[(e2 << 7) + ((((e >> 3) ^ (e2 & 15))) << 3) + (e & 7)] = mt[idx];
  }
  #pragma unroll
  for (int m = 0; m < 2; ++m) {
    const float* wp = m ? wvi : wvr;
    for (int idx = tid; idx < 4096; idx += 512) {
      int e = idx >> 6, d = idx & 63;
      lds[16384 + (m << 12) + (e << 6) + (((d >> 3) ^ (e & 7)) << 3) + (d & 7)] = f2bf(wp[idx]);
    }
  }
  __syncthreads();

  const int lane = tid & 63;
  const int wv   = tid >> 6;
  const int c    = lane & 15;   // MFMA A-row / B-col / C-col
  const int g    = lane >> 4;   // k-chunk group / C-row group

  unsigned short* SY = &lds[24576 + (wv << 11)];

  const float4* mem4 = (const float4*)mem;
  const float4* zr4  = (const float4*)z_real;
  const float4* zi4  = (const float4*)z_imag;
  float4* omem4 = (float4*)out_mem;

  unsigned int active_acc = 0u;
  const int b0 = (int)blockIdx.x * 8 + wv;

  for (int it = 0; it < BPW; ++it) {
    const int b = b0 + it * NWAVES;

    // ---------- global loads: mem row c (cols g*8.. per 32-chunk), z ----------
    float4 cm[8], cz[8];
    #pragma unroll
    for (int t4 = 0; t4 < 4; ++t4) {
      int i4 = b*512 + c*32 + t4*8 + g*2;
      cm[2*t4]   = mem4[i4];
      cm[2*t4+1] = mem4[i4+1];
    }
    {
      int zb = b*16 + g*2;
      cz[0] = zr4[zb];   cz[1] = zr4[zb+1];
      cz[2] = zr4[zb+8]; cz[3] = zr4[zb+9];
      cz[4] = zi4[zb];   cz[5] = zi4[zb+1];
      cz[6] = zi4[zb+8]; cz[7] = zi4[zb+9];
    }

    // ---------- gates + pointer update ----------
    float pu = sigm(ctrl[b*3+0]);
    float po = sigm(ctrl[b*3+1]);
    float st = sigm(ctrl[b*3+2]);
    float tot = pu + po + st + 1e-6f;
    pu /= tot; po /= tot; st /= tot;

    float pm = ptrv[b*16 + ((c+15)&15)];
    float pp = ptrv[b*16 + ((c+ 1)&15)];
    float pc = ptrv[b*16 + c];
    float np = pu*pm + po*pp + st*pc;
    if (g == 0) out_ptr[b*16 + c] = np;
    unsigned long long ball = __ballot(np > 0.1f);
    active_acc += (unsigned int)__popcll(ball & 0xFFFFull);

    // ---------- mem_new (fp32 exact, stored) + xhat fragments ----------
    float omp = 1.0f - pu;
    bf16x8 af[4], afn[2];
    #pragma unroll
    for (int t4 = 0; t4 < 4; ++t4) {
      float4 a0 = cm[2*t4], a1 = cm[2*t4+1];
      float4 z0 = cz[2*t4], z1 = cz[2*t4+1];
      float4 r0, r1;
      r0.x = a0.x*omp + pu*z0.x;  r0.y = a0.y*omp + pu*z0.y;
      r0.z = a0.z*omp + pu*z0.z;  r0.w = a0.w*omp + pu*z0.w;
      r1.x = a1.x*omp + pu*z1.x;  r1.y = a1.y*omp + pu*z1.y;
      r1.z = a1.z*omp + pu*z1.z;  r1.w = a1.w*omp + pu*z1.w;
      int i4 = b*512 + c*32 + t4*8 + g*2;
      omem4[i4]   = r0;
      omem4[i4+1] = r1;
      af[t4][0]=(__bf16)r0.x; af[t4][1]=(__bf16)r0.y; af[t4][2]=(__bf16)r0.z; af[t4][3]=(__bf16)r0.w;
      af[t4][4]=(__bf16)r1.x; af[t4][5]=(__bf16)r1.y; af[t4][6]=(__bf16)r1.z; af[t4][7]=(__bf16)r1.w;
      if (t4 >= 2) {
        afn[t4-2][0]=(__bf16)(-r0.x); afn[t4-2][1]=(__bf16)(-r0.y);
        afn[t4-2][2]=(__bf16)(-r0.z); afn[t4-2][3]=(__bf16)(-r0.w);
        afn[t4-2][4]=(__bf16)(-r1.x); afn[t4-2][5]=(__bf16)(-r1.y);
        afn[t4-2][6]=(__bf16)(-r1.z); afn[t4-2][7]=(__bf16)(-r1.w);
      }
    }

    // ---------- y = xhat * M  (8 col-chunks x 4 K-steps), stage transposed ----------
    #pragma unroll
    for (int n2 = 0; n2 < 8; ++n2) {
      int e2 = (n2 << 4) + c;
      f32x4 acc = {0.f,0.f,0.f,0.f};
      #pragma unroll
      for (int t = 0; t < 4; ++t) {
        bf16x8 bm = *(const bf16x8*)&lds[(e2 << 7) + ((((t << 2) + g) ^ c) << 3)];
        acc = __builtin_amdgcn_mfma_f32_16x16x32_bf16(af[t], bm, acc, 0, 0, 0);
      }
      int chb = (n2 << 1) | (c >> 3);
      #pragma unroll
      for (int i = 0; i < 4; ++i) {
        int s = (g << 2) + i;
        SY[(s << 7) + ((chb ^ s) << 3) + (c & 7)] = f2bf(acc[i]);
      }
    }

    // ---------- scores = y . xhat^T * 1/8 ; softmax over cols ----------
    f32x4 sc = {0.f,0.f,0.f,0.f};
    #pragma unroll
    for (int t = 0; t < 4; ++t) {
      bf16x8 aq = *(const bf16x8*)&SY[(c << 7) + ((((t << 2) + g) ^ c) << 3)];
      sc = __builtin_amdgcn_mfma_f32_16x16x32_bf16(aq, af[t], sc, 0, 0, 0);
    }
    float a4[4];
    #pragma unroll
    for (int i = 0; i < 4; ++i) {
      float s0 = sc[i] * 0.125f;
      float mx = s0;
      mx = fmaxf(mx, __shfl_xor(mx, 1, 64));
      mx = fmaxf(mx, __shfl_xor(mx, 2, 64));
      mx = fmaxf(mx, __shfl_xor(mx, 4, 64));
      mx = fmaxf(mx, __shfl_xor(mx, 8, 64));
      float ex = expf(s0 - mx);
      float sm = ex;
      sm += __shfl_xor(sm, 1, 64);
      sm += __shfl_xor(sm, 2, 64);
      sm += __shfl_xor(sm, 4, 64);
      sm += __shfl_xor(sm, 8, 64);
      a4[i] = ex / sm;            // attn[s=g*4+i][t=c]
    }

    // ---------- w[t] = sum_s np[s] attn[s][t] ----------
    float npi[4];
    #pragma unroll
    for (int i = 0; i < 4; ++i) npi[i] = __shfl(np, (g << 2) + i, 64);
    float pw = a4[0]*npi[0] + a4[1]*npi[1] + a4[2]*npi[2] + a4[3]*npi[3];
    pw += __shfl_xor(pw, 16, 64);
    pw += __shfl_xor(pw, 32, 64);   // all lanes: w[t = c]
    float w4[4];
    #pragma unroll
    for (int i = 0; i < 4; ++i) w4[i] = __shfl(pw, (g << 2) + i, 64);

    // ---------- vhat projection + direct weighted readout ----------
    #pragma unroll
    for (int n = 0; n < 4; ++n) {
      int e = (n << 4) + c, e7 = e & 7, eb = 16384 + (e << 6);
      f32x4 ar = {0.f,0.f,0.f,0.f}, ai = {0.f,0.f,0.f,0.f};
      #pragma unroll
      for (int t = 0; t < 2; ++t) {
        int ch = (((t << 2) + g) ^ e7) << 3;
        bf16x8 fr = *(const bf16x8*)&lds[eb + ch];
        bf16x8 fi = *(const bf16x8*)&lds[eb + 4096 + ch];
        ar = __builtin_amdgcn_mfma_f32_16x16x32_bf16(af[t],   fr, ar, 0,0,0);
        ai = __builtin_amdgcn_mfma_f32_16x16x32_bf16(af[t],   fi, ai, 0,0,0);
        ar = __builtin_amdgcn_mfma_f32_16x16x32_bf16(afn[t],  fi, ar, 0,0,0);
        ai = __builtin_amdgcn_mfma_f32_16x16x32_bf16(af[t+2], fr, ai, 0,0,0);
      }
      float prr = ar[0]*w4[0] + ar[1]*w4[1] + ar[2]*w4[2] + ar[3]*w4[3];
      float pri = ai[0]*w4[0] + ai[1]*w4[1] + ai[2]*w4[2] + ai[3]*w4[3];
      prr += __shfl_xor(prr, 16, 64);
      prr += __shfl_xor(prr, 32, 64);
      pri += __shfl_xor(pri, 16, 64);
      pri += __shfl_xor(pri, 32, 64);
      if (g == 0) {
        out_zr[b*64 + (n << 4) + c] = prr;
        out_zi[b*64 + (n << 4) + c] = pri;
      }
    }
  }

  if (lane == 0) atomicAdd(ws_cnt, active_acc);
}

extern "C" void kernel_launch(void* const* d_in, const int* in_sizes, int n_in,
                              void* d_out, int out_size, void* d_ws, size_t ws_size,
                              hipStream_t stream) {
  const float* z_real = (const float*)d_in[0];
  const float* z_imag = (const float*)d_in[1];
  const float* memp   = (const float*)d_in[2];
  const float* ptrv   = (const float*)d_in[3];
  const float* ctrl   = (const float*)d_in[4];
  const float* wq_r   = (const float*)d_in[5];
  const float* wq_i   = (const float*)d_in[6];
  const float* wk_r   = (const float*)d_in[7];
  const float* wk_i   = (const float*)d_in[8];
  const float* wv_r   = (const float*)d_in[9];
  const float* wv_i   = (const float*)d_in[10];

  float* out     = (float*)d_out;
  float* out_zr  = out;
  float* out_zi  = out + 2097152;
  float* out_mem = out + 4194304;
  float* out_ptr = out + 71303168;
  float* out_sc  = out + 71827456;

  unsigned int*   cnt = (unsigned int*)d_ws;
  unsigned short* mt  = (unsigned short*)((char*)d_ws + 1024);  // needs ws_size >= 33792

  ems_zero<<<1, 64, 0, stream>>>(cnt);
  ems_mt<<<128, 128, 0, stream>>>(wq_r, wq_i, wk_r, wk_i, mt);
  ems_main<<<GRID_WG, 512, 0, stream>>>(z_real, z_imag, memp, ptrv, ctrl,
                                        wv_r, wv_i, mt,
                                        out_zr, out_zi, out_mem, out_ptr, cnt);
  ems_fin<<<1, 64, 0, stream>>>(cnt, out_sc);
}